// Round 9
// baseline (199.765 us; speedup 1.0000x reference)
//
#include <hip/hip_runtime.h>
#include <hip/hip_bf16.h>

typedef unsigned short u16;
typedef unsigned long long u64t;
typedef __attribute__((ext_vector_type(8))) short bhalf8;   // 8 x bf16 (4 VGPRs)
typedef __attribute__((ext_vector_type(4))) short bhalf4;   // 4 x bf16 (2 VGPRs)
typedef __attribute__((ext_vector_type(4))) float f32x4;    // MFMA accumulator

#define MFMA16(a, b, c) __builtin_amdgcn_mfma_f32_16x16x32_bf16((a), (b), (c), 0, 0, 0)

#if __has_builtin(__builtin_amdgcn_mfma_f32_16x16x16bf16_1k)
#define HAVE_K16 1
#define MFMAK16(a, b, c) __builtin_amdgcn_mfma_f32_16x16x16bf16_1k((a), (b), (c), 0, 0, 0)
#elif __has_builtin(__builtin_amdgcn_mfma_f32_16x16x16_bf16)
#define HAVE_K16 1
#define MFMAK16(a, b, c) __builtin_amdgcn_mfma_f32_16x16x16_bf16((a), (b), (c), 0, 0, 0)
#else
#define HAVE_K16 0
#endif

#if __has_builtin(__builtin_amdgcn_perm)
#define HAVE_PERM 1
#else
#define HAVE_PERM 0
#endif

#define BB 2
#define SS 2048
#define DD 512
#define HH 8
#define HD 64
#define NT (BB * SS)
#define LOG2E 1.44269504f

#if __has_builtin(__builtin_amdgcn_exp2f)
#define EXP2(x) __builtin_amdgcn_exp2f(x)
#else
#define EXP2(x) exp2f(x)
#endif

__device__ __forceinline__ u16 f2b(float f) {
    unsigned u = __builtin_bit_cast(unsigned, f);
    unsigned r = (u + 0x7fffu + ((u >> 16) & 1u)) >> 16;
    return (u16)r;
}

// Pack two fp32 -> two bf16 (round-half-up) in one dword: 2x v_add + 1x v_perm.
// Result: low16 = bf16(f0), high16 = bf16(f1).
__device__ __forceinline__ unsigned pk2bf(float f0, float f1) {
#if HAVE_PERM
    unsigned a0 = __builtin_bit_cast(unsigned, f0) + 0x8000u;
    unsigned a1 = __builtin_bit_cast(unsigned, f1) + 0x8000u;
    return __builtin_amdgcn_perm(a1, a0, 0x07060302u);
#else
    return (unsigned)f2b(f0) | ((unsigned)f2b(f1) << 16);
#endif
}

__device__ __forceinline__ void gl2lds16(const u16* g, u16* l) {
    u16* gn = (u16*)g;
    __builtin_amdgcn_global_load_lds((__attribute__((address_space(1))) void*)gn,
                                     (__attribute__((address_space(3))) void*)l, 16, 0, 0);
}

// ---------------------------------------------------------------------------
// Fused prep: weight transposes (jobs 0..3071) + qkv bias concat (3072..3077)
// + LayerNorm1 rows (3078..4101; 4 rows/block). LN is independent of weights.
// ---------------------------------------------------------------------------
__global__ __launch_bounds__(256) void k_prep(const float* __restrict__ Wq, const float* __restrict__ Wk,
                                              const float* __restrict__ Wv, const float* __restrict__ Wp,
                                              const float* __restrict__ W1, const float* __restrict__ W2,
                                              const float* __restrict__ bq, const float* __restrict__ bk,
                                              const float* __restrict__ bv,
                                              u16* __restrict__ WqkvT, u16* __restrict__ WpT,
                                              u16* __restrict__ W1T, u16* __restrict__ W2T,
                                              float* __restrict__ biasqkv,
                                              const float* __restrict__ x, const float* __restrict__ g1,
                                              const float* __restrict__ be1, u16* __restrict__ xn) {
    int j = blockIdx.x;
    int t = threadIdx.x;
    if (j >= 3078) {                           // LayerNorm1: 4 rows per block
        int wave = t >> 6, lane = t & 63;
        int row = (j - 3078) * 4 + wave;
        const float* xr = x + (size_t)row * DD;
        int c = lane * 8;
        float4 v0 = *(const float4*)(xr + c);
        float4 v1 = *(const float4*)(xr + c + 4);
        float s  = v0.x + v0.y + v0.z + v0.w + v1.x + v1.y + v1.z + v1.w;
        float sq = v0.x*v0.x + v0.y*v0.y + v0.z*v0.z + v0.w*v0.w
                 + v1.x*v1.x + v1.y*v1.y + v1.z*v1.z + v1.w*v1.w;
#pragma unroll
        for (int m = 1; m < 64; m <<= 1) {
            s  += __shfl_xor(s, m);
            sq += __shfl_xor(sq, m);
        }
        float mean = s * (1.0f / DD);
        float var  = sq * (1.0f / DD) - mean * mean;
        float rstd = rsqrtf(var + 1e-5f);
        float4 g0 = *(const float4*)(g1 + c);
        float4 g4 = *(const float4*)(g1 + c + 4);
        float4 b0 = *(const float4*)(be1 + c);
        float4 b4 = *(const float4*)(be1 + c + 4);
        float xv[8] = {v0.x, v0.y, v0.z, v0.w, v1.x, v1.y, v1.z, v1.w};
        float gv[8] = {g0.x, g0.y, g0.z, g0.w, g4.x, g4.y, g4.z, g4.w};
        float bv2[8] = {b0.x, b0.y, b0.z, b0.w, b4.x, b4.y, b4.z, b4.w};
        union { bhalf8 v; u16 u[8]; } pk;
#pragma unroll
        for (int i = 0; i < 8; i++) pk.u[i] = f2b((xv[i] - mean) * rstd * gv[i] + bv2[i]);
        *(bhalf8*)(xn + (size_t)row * DD + c) = pk.v;
        return;
    }
    int tx = t & 31, ty = t >> 5;              // (32,8) mapping
    if (j >= 3072) {                           // bias concat
        int i = (j - 3072) * 256 + ty * 32 + tx;
        biasqkv[i] = (i < 512) ? bq[i] : (i < 1024) ? bk[i - 512] : bv[i - 1024];
        return;
    }
    __shared__ float tile[32][33];
    const float* src; u16* dst; int R, C, tr, tc;
    if (j < 768) {            // Wq/Wk/Wv per-head [512,64] -> [64,512]
        int m = j >> 8, rem = j & 255, h = rem >> 5, tl = rem & 31;
        tr = tl >> 1; tc = tl & 1;
        src = (m == 0 ? Wq : (m == 1 ? Wk : Wv)) + h * 32768;
        dst = WqkvT + m * 262144 + h * 32768;
        R = 512; C = 64;
    } else if (j < 1024) { int tl = j - 768;  tr = tl >> 4; tc = tl & 15; src = Wp; dst = WpT; R = 512;  C = 512;  }
    else if (j < 2048)   { int tl = j - 1024; tr = tl >> 6; tc = tl & 63; src = W1; dst = W1T; R = 512;  C = 2048; }
    else                 { int tl = j - 2048; tr = tl >> 4; tc = tl & 15; src = W2; dst = W2T; R = 2048; C = 512;  }
    int c = tc * 32 + tx;
#pragma unroll
    for (int i = 0; i < 4; i++)
        tile[ty + i * 8][tx] = src[(size_t)(tr * 32 + ty + i * 8) * C + c];
    __syncthreads();
    int r2 = tr * 32 + tx;
#pragma unroll
    for (int i = 0; i < 4; i++)
        dst[(size_t)(tc * 32 + ty + i * 8) * R + r2] = f2b(tile[tx][ty + i * 8]);
}

// ---------------------------------------------------------------------------
// LayerNorm: one wave per 512-col row; fp32 in, bf16 out  (used for LN2)
// ---------------------------------------------------------------------------
__global__ __launch_bounds__(256) void k_layernorm(const float* __restrict__ x,
                                                   const float* __restrict__ g,
                                                   const float* __restrict__ be,
                                                   u16* __restrict__ out) {
    int wave = threadIdx.x >> 6, lane = threadIdx.x & 63;
    int row = blockIdx.x * 4 + wave;
    const float* xr = x + (size_t)row * DD;
    int c = lane * 8;
    float4 v0 = *(const float4*)(xr + c);
    float4 v1 = *(const float4*)(xr + c + 4);
    float s  = v0.x + v0.y + v0.z + v0.w + v1.x + v1.y + v1.z + v1.w;
    float sq = v0.x*v0.x + v0.y*v0.y + v0.z*v0.z + v0.w*v0.w
             + v1.x*v1.x + v1.y*v1.y + v1.z*v1.z + v1.w*v1.w;
#pragma unroll
    for (int m = 1; m < 64; m <<= 1) {
        s  += __shfl_xor(s, m);
        sq += __shfl_xor(sq, m);
    }
    float mean = s * (1.0f / DD);
    float var  = sq * (1.0f / DD) - mean * mean;
    float rstd = rsqrtf(var + 1e-5f);
    float4 g0 = *(const float4*)(g + c);
    float4 g1 = *(const float4*)(g + c + 4);
    float4 b0 = *(const float4*)(be + c);
    float4 b1 = *(const float4*)(be + c + 4);
    float xv[8] = {v0.x, v0.y, v0.z, v0.w, v1.x, v1.y, v1.z, v1.w};
    float gv[8] = {g0.x, g0.y, g0.z, g0.w, g1.x, g1.y, g1.z, g1.w};
    float bv[8] = {b0.x, b0.y, b0.z, b0.w, b1.x, b1.y, b1.z, b1.w};
    union { bhalf8 v; u16 u[8]; } pk;
#pragma unroll
    for (int i = 0; i < 8; i++) pk.u[i] = f2b((xv[i] - mean) * rstd * gv[i] + bv[i]);
    *(bhalf8*)(out + (size_t)row * DD + c) = pk.v;
}

// ---------------------------------------------------------------------------
// bf16 MFMA GEMM, BMxBN tile, BK=64, gl2lds staging (8-row x 64-col 1KB chunks)
// T3 minimum 2-phase (round-6 proven): double-buffered LDS (static As0/As1),
// next tile's global_load_lds issued BEFORE compute, ONE barrier per K-step
// after compute. Requires kLen/64 even (call sites: 8, 8, 8, 32 steps).
// MODE 0: qkv scatter (q scaled by log2e, v transposed [bh,hd,S])
// MODE 1: out fp32 = val + bias + resid
// MODE 2: out bf16 = relu(val + bias)
// ---------------------------------------------------------------------------
template<int BM, int BN, int WR, int WC, int MI, int NI, int MODE>
__global__ __launch_bounds__(256) void k_gemm(const u16* __restrict__ A, const u16* __restrict__ Bt,
                                              const float* __restrict__ bias,
                                              int lda, int ldb, int kLen, int N,
                                              const float* __restrict__ resid,
                                              float* __restrict__ outF, u16* __restrict__ outB,
                                              u16* __restrict__ qd, u16* __restrict__ kd,
                                              u16* __restrict__ vtd) {
    constexpr int WM = MI * 16;
    constexpr int WN = NI * 16;
    static_assert(WR * WM == BM && WC * WN == BN && WR * WC == 4, "cfg");
    constexpr int ACH = BM / 32;          // A staging chunks per wave (8 rows each)
    constexpr int BCH = BN / 32;
    __shared__ u16 As0[BM * 64];
    __shared__ u16 Bs0[BN * 64];
    __shared__ u16 As1[BM * 64];
    __shared__ u16 Bs1[BN * 64];
    int t = threadIdx.x;
    int wave = t >> 6, lane = t & 63, quad = lane >> 4, l16 = lane & 15;
    int wr, wc;
    if (WC == 1)      { wr = wave; wc = 0; }
    else if (WR == 1) { wr = 0;    wc = wave; }
    else              { wr = wave >> 1; wc = wave & 1; }
    int m0 = blockIdx.y * BM, n0 = blockIdx.x * BN;

    f32x4 acc[MI][NI] = {};

    int srow = lane >> 3;                 // 0..7
    int scol = (lane & 7) * 8;
    const u16* Ag = A  + (size_t)(m0 + srow) * lda + scol;
    const u16* Bg = Bt + (size_t)(n0 + srow) * ldb + scol;

    auto stage = [&](u16* Asd, u16* Bsd, int k0) {
#pragma unroll
        for (int c = 0; c < ACH; c++) {
            int ch = wave * ACH + c;
            gl2lds16(Ag + (size_t)(ch * 8) * lda + k0, &Asd[ch * 512]);
        }
#pragma unroll
        for (int c = 0; c < BCH; c++) {
            int ch = wave * BCH + c;
            gl2lds16(Bg + (size_t)(ch * 8) * ldb + k0, &Bsd[ch * 512]);
        }
    };
    auto compute = [&](const u16* Asd, const u16* Bsd) {
#pragma unroll
        for (int h = 0; h < 2; h++) {
            bhalf8 af[MI], bf[NI];
#pragma unroll
            for (int mi = 0; mi < MI; mi++)
                af[mi] = *(const bhalf8*)&Asd[(wr * WM + mi * 16 + l16) * 64 + h * 32 + quad * 8];
#pragma unroll
            for (int ni = 0; ni < NI; ni++)
                bf[ni] = *(const bhalf8*)&Bsd[(wc * WN + ni * 16 + l16) * 64 + h * 32 + quad * 8];
#pragma unroll
            for (int mi = 0; mi < MI; mi++)
#pragma unroll
                for (int ni = 0; ni < NI; ni++)
                    acc[mi][ni] = MFMA16(af[mi], bf[ni], acc[mi][ni]);
        }
    };

    int nt = kLen >> 6;                   // K-steps (even at all call sites)
    stage(As0, Bs0, 0);                   // prologue
    __syncthreads();                      // drain tile 0
    for (int kt = 0; kt < nt; kt += 2) {
        if (kt + 1 < nt) stage(As1, Bs1, (kt + 1) << 6);   // issue next (flies during MFMA)
        compute(As0, Bs0);
        __syncthreads();                  // drain kt+1 loads + protect As0 reuse
        if (kt + 1 < nt) {
            if (kt + 2 < nt) stage(As0, Bs0, (kt + 2) << 6);
            compute(As1, Bs1);
            __syncthreads();
        }
    }

#pragma unroll
    for (int mi = 0; mi < MI; mi++)
#pragma unroll
        for (int ni = 0; ni < NI; ni++) {
            f32x4 a = acc[mi][ni];
            int gc = n0 + wc * WN + ni * 16 + l16;
            int gr0 = m0 + wr * WM + mi * 16 + quad * 4;
            float bsv = bias[gc];
            if (MODE == 0) {
                int mm = gc >> 9, cc = gc & 511;
                int hh = cc >> 6, e = cc & 63;
                int b = gr0 >> 11, s0 = gr0 & 2047;
                if (mm == 2) {
                    u64t pk = 0;
#pragma unroll
                    for (int r = 0; r < 4; r++) pk |= (u64t)f2b(a[r] + bsv) << (16 * r);
                    *(u64t*)&vtd[((size_t)(b * HH + hh) * HD + e) * SS + s0] = pk;
                } else if (mm == 0) {
#pragma unroll
                    for (int r = 0; r < 4; r++)
                        qd[((size_t)(b * HH + hh) * SS + s0 + r) * HD + e] = f2b((a[r] + bsv) * LOG2E);
                } else {
#pragma unroll
                    for (int r = 0; r < 4; r++)
                        kd[((size_t)(b * HH + hh) * SS + s0 + r) * HD + e] = f2b(a[r] + bsv);
                }
            } else if (MODE == 1) {
#pragma unroll
                for (int r = 0; r < 4; r++) {
                    size_t idx = (size_t)(gr0 + r) * N + gc;
                    outF[idx] = a[r] + bsv + resid[idx];
                }
            } else {
#pragma unroll
                for (int r = 0; r < 4; r++)
                    outB[(size_t)(gr0 + r) * N + gc] = f2b(fmaxf(a[r] + bsv, 0.0f));
            }
        }
}

// ---------------------------------------------------------------------------
// Flash attention v5: 512 threads = 8 waves in 2 kv-groups.
// q-tile 128 (32 q-rows/wave), kv-tile 128 split across groups (nt 0-3/4-7).
// S^T trick, register prefetch, split-KV x2, no-max softmax (q pre-scaled by
// log2e). Group 1 merges into group 0 through dead LDS at the epilogue.
// Kept: T5 s_setprio, f32x4 row-sum partials, pk2bf pack.
// This round: K/V LDS DOUBLE-BUFFER (T3 applied to attention) — one barrier
// per kv-tile instead of two; LDS stores of tile t+1 overlap compute on tile
// t. LDS 71,680 B -> still 2 blocks/CU. Bit-identical numerics.
// ---------------------------------------------------------------------------
__global__ __launch_bounds__(512) void k_attention(const u16* __restrict__ q,
                                                   const u16* __restrict__ k,
                                                   const u16* __restrict__ vt,
                                                   float* __restrict__ Opart,
                                                   float* __restrict__ lsum) {
    __shared__ u16 sm[35840];                 // 71,680 B: 2x (Ks 9216 + Vs 8704 u16)
    u16* Ks0 = sm;                            // [kv][hd] 128*72
    u16* Vs0 = sm + 9216;                     // [hd][kv] 64*136
    u16* Ks1 = sm + 17920;
    u16* Vs1 = sm + 27136;
    float* Ored = (float*)sm;                 // epilogue overlay: 8192 f32 (32 KB, in buf0)
    float* Lred = (float*)sm + 8192;          // 128 f32

    int bh = blockIdx.x, qt = blockIdx.y, kspl = blockIdx.z;
    int t = threadIdx.x, wave = t >> 6, lane = t & 63, quad = lane >> 4, l16 = lane & 15;
    int g = wave >> 2, qw = wave & 3;         // kv-group, q-subtile
    const u16* qb = q  + (size_t)bh * SS * HD;
    const u16* kb = k  + (size_t)bh * SS * HD;
    const u16* vb = vt + (size_t)bh * HD * SS;

    // two q-chunks of 16 rows per wave (identical across groups)
    bhalf8 qfa0, qfa1, qfb0, qfb1;
    {
        int r0 = qt * 128 + qw * 32 + l16;
        qfa0 = *(const bhalf8*)(qb + (size_t)r0 * HD + quad * 8);
        qfa1 = *(const bhalf8*)(qb + (size_t)r0 * HD + 32 + quad * 8);
        qfb0 = *(const bhalf8*)(qb + (size_t)(r0 + 16) * HD + quad * 8);
        qfb1 = *(const bhalf8*)(qb + (size_t)(r0 + 16) * HD + 32 + quad * 8);
    }

    f32x4 oacc[2][4] = {};
    f32x4 rsa4 = {}, rsb4 = {};

    // staging: 512 threads, 32B each for K and V
    int kr = t >> 2, kc = (t & 3) * 16;       // K: 128 rows x 64 cols
    int vr = t >> 3, vc = (t & 7) * 16;       // V: 64 rows x 128 cols
    const u16* kp = kb + ((size_t)kspl * 1024 + kr) * HD + kc;
    const u16* vp = vb + (size_t)vr * SS + kspl * 1024 + vc;
    int koff = kr * 72 + kc;
    int voff = vr * 136 + vc;

    bhalf8 kreg[2], vreg[2];
#pragma unroll
    for (int i = 0; i < 2; i++) {             // tile 0 -> regs
        kreg[i] = *(const bhalf8*)(kp + i * 8);
        vreg[i] = *(const bhalf8*)(vp + i * 8);
    }
#pragma unroll
    for (int i = 0; i < 2; i++) {             // tile 0 -> buf0
        *(bhalf8*)(&Ks0[koff] + i * 8) = kreg[i];
        *(bhalf8*)(&Vs0[voff] + i * 8) = vreg[i];
    }
    __syncthreads();
#pragma unroll
    for (int i = 0; i < 2; i++) {             // tile 1 -> regs (always exists)
        kreg[i] = *(const bhalf8*)(kp + (size_t)128 * HD + i * 8);
        vreg[i] = *(const bhalf8*)(vp + 128 + i * 8);
    }

    auto att_step = [&](const u16* Ksb, const u16* Vsb) {
#pragma unroll
        for (int nt2 = 0; nt2 < 4; nt2++) {
            int nt = g * 4 + nt2;
            bhalf8 kf0 = *(const bhalf8*)&Ksb[(nt * 16 + l16) * 72 + quad * 8];
            bhalf8 kf1 = *(const bhalf8*)&Ksb[(nt * 16 + l16) * 72 + 32 + quad * 8];
            // S^T = K·Q^T (C-layout: col=l16=q, row=quad*4+r=kv)
            f32x4 sa = {}, sb = {};
            __builtin_amdgcn_s_setprio(1);
            sa = MFMA16(kf0, qfa0, sa);
            sa = MFMA16(kf1, qfa1, sa);
            sb = MFMA16(kf0, qfb0, sb);
            sb = MFMA16(kf1, qfb1, sb);
            __builtin_amdgcn_s_setprio(0);
#if HAVE_K16
            float p0[4], p1[4];
#pragma unroll
            for (int r = 0; r < 4; r++) {
                p0[r] = EXP2(sa[r]);
                p1[r] = EXP2(sb[r]);
            }
#pragma unroll
            for (int r = 0; r < 4; r++) { rsa4[r] += p0[r]; rsb4[r] += p1[r]; }
            union { bhalf4 v; unsigned w[2]; } pa, pb;
            pa.w[0] = pk2bf(p0[0], p0[1]);
            pa.w[1] = pk2bf(p0[2], p0[3]);
            pb.w[0] = pk2bf(p1[0], p1[1]);
            pb.w[1] = pk2bf(p1[2], p1[3]);
            __builtin_amdgcn_s_setprio(1);
#pragma unroll
            for (int et = 0; et < 4; et++) {
                bhalf4 vf = *(const bhalf4*)&Vsb[(et * 16 + l16) * 136 + nt * 16 + quad * 4];
                oacc[0][et] = MFMAK16(pa.v, vf, oacc[0][et]);
                oacc[1][et] = MFMAK16(pb.v, vf, oacc[1][et]);
            }
            __builtin_amdgcn_s_setprio(0);
#else
            float p0[4], p1[4];
#pragma unroll
            for (int r = 0; r < 4; r++) {
                p0[r] = EXP2(sa[r]);
                p1[r] = EXP2(sb[r]);
                rsa4[r] += p0[r]; rsb4[r] += p1[r];
            }
            union { bhalf8 v; unsigned w[4]; } pa, pb;
            pa.w[0] = pk2bf(p0[0], p0[1]);
            pa.w[1] = pk2bf(p0[2], p0[3]);
            pa.w[2] = 0; pa.w[3] = 0;
            pb.w[0] = pk2bf(p1[0], p1[1]);
            pb.w[1] = pk2bf(p1[2], p1[3]);
            pb.w[2] = 0; pb.w[3] = 0;
            __builtin_amdgcn_s_setprio(1);
#pragma unroll
            for (int et = 0; et < 4; et++) {
                union { bhalf8 v; bhalf4 h[2]; } vf;
                vf.h[0] = *(const bhalf4*)&Vsb[(et * 16 + l16) * 136 + nt * 16 + quad * 4];
                vf.h[1] = (bhalf4){0, 0, 0, 0};
                oacc[0][et] = MFMA16(pa.v, vf.v, oacc[0][et]);
                oacc[1][et] = MFMA16(pb.v, vf.v, oacc[1][et]);
            }
            __builtin_amdgcn_s_setprio(0);
#endif
        }
    };

    // Double-buffered main loop: one barrier per kv-tile. Regs hold tile it+1
    // at the top of each even step.
    for (int it = 0; it < 8; it += 2) {
        // even: store tile it+1 -> buf1 (writes overlap compute on buf0)
#pragma unroll
        for (int i = 0; i < 2; i++) {
            *(bhalf8*)(&Ks1[koff] + i * 8) = kreg[i];
            *(bhalf8*)(&Vs1[voff] + i * 8) = vreg[i];
        }
        if (it + 2 < 8) {                 // prefetch tile it+2 -> regs
            const u16* kn = kp + (size_t)(it + 2) * 128 * HD;
            const u16* vn = vp + (it + 2) * 128;
#pragma unroll
            for (int i = 0; i < 2; i++) {
                kreg[i] = *(const bhalf8*)(kn + i * 8);
                vreg[i] = *(const bhalf8*)(vn + i * 8);
            }
        }
        att_step(Ks0, Vs0);               // compute tile it
        __syncthreads();
        // odd: store tile it+2 -> buf0, compute tile it+1 from buf1
        if (it + 2 < 8) {
#pragma unroll
            for (int i = 0; i < 2; i++) {
                *(bhalf8*)(&Ks0[koff] + i * 8) = kreg[i];
                *(bhalf8*)(&Vs0[voff] + i * 8) = vreg[i];
            }
            if (it + 3 < 8) {             // prefetch tile it+3 -> regs
                const u16* kn = kp + (size_t)(it + 3) * 128 * HD;
                const u16* vn = vp + (it + 3) * 128;
#pragma unroll
                for (int i = 0; i < 2; i++) {
                    kreg[i] = *(const bhalf8*)(kn + i * 8);
                    vreg[i] = *(const bhalf8*)(vn + i * 8);
                }
            }
        }
        att_step(Ks1, Vs1);               // compute tile it+1
        __syncthreads();
    }

    float rsa = (rsa4[0] + rsa4[1]) + (rsa4[2] + rsa4[3]);
    float rsb = (rsb4[0] + rsb4[1]) + (rsb4[2] + rsb4[3]);
    rsa += __shfl_xor(rsa, 16); rsa += __shfl_xor(rsa, 32);
    rsb += __shfl_xor(rsb, 16); rsb += __shfl_xor(rsb, 32);

    // all K/V LDS dead (loop ended with barrier); overlay buf0 as Ored/Lred
    if (g == 1) {
#pragma unroll
        for (int qc = 0; qc < 2; qc++)
#pragma unroll
            for (int et = 0; et < 4; et++)
#pragma unroll
                for (int r = 0; r < 4; r++)
                    Ored[(qw * 32 + qc * 16 + quad * 4 + r) * 64 + et * 16 + l16] = oacc[qc][et][r];
        if (quad == 0) {
            Lred[qw * 32 + l16]      = rsa;
            Lred[qw * 32 + 16 + l16] = rsb;
        }
    }
    __syncthreads();
    if (g == 0) {
#pragma unroll
        for (int qc = 0; qc < 2; qc++) {
            int sbase = qt * 128 + qw * 32 + qc * 16;
            float* Ob = Opart + ((size_t)(kspl * 16 + bh) * SS + sbase) * HD;
#pragma unroll
            for (int et = 0; et < 4; et++)
#pragma unroll
                for (int r = 0; r < 4; r++) {
                    float v = oacc[qc][et][r]
                            + Ored[(qw * 32 + qc * 16 + quad * 4 + r) * 64 + et * 16 + l16];
                    Ob[(quad * 4 + r) * HD + et * 16 + l16] = v;
                }
            if (quad == 0)
                lsum[(size_t)(kspl * 16 + bh) * SS + sbase + l16] =
                    (qc == 0 ? rsa : rsb) + Lred[qw * 32 + qc * 16 + l16];
        }
    }
}

// combine: oc[b,s,h*64+e] = (O0+O1)/(l0+l1), bf16
__global__ __launch_bounds__(256) void k_combine(const float* __restrict__ Opart,
                                                 const float* __restrict__ lsum,
                                                 u16* __restrict__ oc) {
    int tid = blockIdx.x * 256 + threadIdx.x;
    int c4 = tid & 15, s = (tid >> 4) & 2047, bh = tid >> 15;
    size_t i0 = ((size_t)bh * SS + s) * HD + c4 * 4;
    float4 p0 = *(const float4*)(Opart + i0);
    float4 p1 = *(const float4*)(Opart + (size_t)16 * SS * HD + i0);
    float l = lsum[(size_t)bh * SS + s] + lsum[(size_t)16 * SS + (size_t)bh * SS + s];
    float inv = 1.0f / l;
    u64t pk = 0;
    pk |= (u64t)f2b((p0.x + p1.x) * inv);
    pk |= (u64t)f2b((p0.y + p1.y) * inv) << 16;
    pk |= (u64t)f2b((p0.z + p1.z) * inv) << 32;
    pk |= (u64t)f2b((p0.w + p1.w) * inv) << 48;
    int b = bh >> 3, h = bh & 7;
    *(u64t*)&oc[((size_t)b * SS + s) * DD + h * HD + c4 * 4] = pk;
}

// ---------------------------------------------------------------------------
extern "C" void kernel_launch(void* const* d_in, const int* in_sizes, int n_in,
                              void* d_out, int out_size, void* d_ws, size_t ws_size,
                              hipStream_t stream) {
    const float* x   = (const float*)d_in[0];
    const float* Wq  = (const float*)d_in[1];
    const float* bq  = (const float*)d_in[2];
    const float* Wk  = (const float*)d_in[3];
    const float* bk  = (const float*)d_in[4];
    const float* Wv  = (const float*)d_in[5];
    const float* bv  = (const float*)d_in[6];
    const float* Wp  = (const float*)d_in[7];
    const float* bp  = (const float*)d_in[8];
    const float* W1  = (const float*)d_in[9];
    const float* b1  = (const float*)d_in[10];
    const float* W2  = (const float*)d_in[11];
    const float* b2  = (const float*)d_in[12];
    const float* g1  = (const float*)d_in[13];
    const float* be1 = (const float*)d_in[14];
    const float* g2  = (const float*)d_in[15];
    const float* be2 = (const float*)d_in[16];

    char* ws = (char*)d_ws;
    u16*   WqkvT   = (u16*)(ws + 0);                    // 1,572,864
    u16*   WpT     = (u16*)(ws + 1572864);              //   524,288
    u16*   W1T     = (u16*)(ws + 2097152);              // 2,097,152
    u16*   W2T     = (u16*)(ws + 4194304);              // 2,097,152
    float* biasqkv = (float*)(ws + 6291456);            // 6,144
    u16*   xn      = (u16*)(ws + 6297600);              // 4,194,304 (reused: lsum)
    u16*   qB      = (u16*)(ws + 10491904);             // 4,194,304
    u16*   kB      = (u16*)(ws + 14686208);             // 4,194,304
    u16*   vTb     = (u16*)(ws + 18880512);             // 4,194,304  [bh,hd,S]
    u16*   oc      = (u16*)(ws + 23074816);             // 4,194,304
    float* x1      = (float*)(ws + 27269120);           // 8,388,608
    u16*   xn2     = (u16*)(ws + 35657728);             // 4,194,304
    u16*   hbuf    = (u16*)(ws + 39852032);             // 16,777,216 (Opart before MLP1)
    float* Opart   = (float*)hbuf;
    float* lsum    = (float*)xn;

    // prep (weights + bias concat) fused with LN1
    k_prep<<<4102, 256, 0, stream>>>(Wq, Wk, Wv, Wp, W1, W2, bq, bk, bv,
                                     WqkvT, WpT, W1T, W2T, biasqkv,
                                     x, g1, be1, xn);
    // QKV: 128x128 BK=64 dbuf-prefetch, grid 384
    k_gemm<128, 128, 2, 2, 4, 4, 0><<<dim3(12, 32), 256, 0, stream>>>(
        xn, WqkvT, biasqkv, 512, 512, 512, 1536, nullptr, nullptr, nullptr, qB, kB, vTb);
    // attention: 8-wave v5 (K/V LDS dbuf, 1 barrier/tile), split-KV x2, grid 512
    k_attention<<<dim3(16, 16, 2), 512, 0, stream>>>(qB, kB, vTb, Opart, lsum);
    k_combine<<<2048, 256, 0, stream>>>(Opart, lsum, oc);
    // proj + residual: 64x64 BK=64 dbuf-prefetch, grid 512
    k_gemm<64, 64, 2, 2, 2, 2, 1><<<dim3(8, 64), 256, 0, stream>>>(
        oc, WpT, bp, 512, 512, 512, 512, x, x1, nullptr, nullptr, nullptr, nullptr);
    k_layernorm<<<NT / 4, 256, 0, stream>>>(x1, g2, be2, xn2);
    // MLP1: 128x128 BK=64 dbuf-prefetch, grid 512
    k_gemm<128, 128, 2, 2, 4, 4, 2><<<dim3(16, 32), 256, 0, stream>>>(
        xn2, W1T, b1, 512, 512, 512, 2048, nullptr, nullptr, hbuf, nullptr, nullptr, nullptr);
    // MLP2 + residual: 64x64 BK=64 dbuf-prefetch, K=2048, grid 512
    // (round-7 falsified 128x64 @ 1 block/CU: 2 blocks/CU wins — keep 64x64)
    k_gemm<64, 64, 2, 2, 2, 2, 1><<<dim3(8, 64), 256, 0, stream>>>(
        hbuf, W2T, b2, 2048, 2048, 2048, 512, x1, (float*)d_out, nullptr, nullptr, nullptr, nullptr);
}

// Round 10
// 193.941 us; speedup vs baseline: 1.0300x; 1.0300x over previous
//
#include <hip/hip_runtime.h>
#include <hip/hip_bf16.h>

typedef unsigned short u16;
typedef unsigned long long u64t;
typedef __attribute__((ext_vector_type(8))) short bhalf8;   // 8 x bf16 (4 VGPRs)
typedef __attribute__((ext_vector_type(4))) short bhalf4;   // 4 x bf16 (2 VGPRs)
typedef __attribute__((ext_vector_type(4))) float f32x4;    // MFMA accumulator

#define MFMA16(a, b, c) __builtin_amdgcn_mfma_f32_16x16x32_bf16((a), (b), (c), 0, 0, 0)

#if __has_builtin(__builtin_amdgcn_mfma_f32_16x16x16bf16_1k)
#define HAVE_K16 1
#define MFMAK16(a, b, c) __builtin_amdgcn_mfma_f32_16x16x16bf16_1k((a), (b), (c), 0, 0, 0)
#elif __has_builtin(__builtin_amdgcn_mfma_f32_16x16x16_bf16)
#define HAVE_K16 1
#define MFMAK16(a, b, c) __builtin_amdgcn_mfma_f32_16x16x16_bf16((a), (b), (c), 0, 0, 0)
#else
#define HAVE_K16 0
#endif

#if __has_builtin(__builtin_amdgcn_perm)
#define HAVE_PERM 1
#else
#define HAVE_PERM 0
#endif

#define BB 2
#define SS 2048
#define DD 512
#define HH 8
#define HD 64
#define NT (BB * SS)
#define LOG2E 1.44269504f

#if __has_builtin(__builtin_amdgcn_exp2f)
#define EXP2(x) __builtin_amdgcn_exp2f(x)
#else
#define EXP2(x) exp2f(x)
#endif

__device__ __forceinline__ u16 f2b(float f) {
    unsigned u = __builtin_bit_cast(unsigned, f);
    unsigned r = (u + 0x7fffu + ((u >> 16) & 1u)) >> 16;
    return (u16)r;
}

// Pack two fp32 -> two bf16 (round-half-up) in one dword: 2x v_add + 1x v_perm.
// Result: low16 = bf16(f0), high16 = bf16(f1).
__device__ __forceinline__ unsigned pk2bf(float f0, float f1) {
#if HAVE_PERM
    unsigned a0 = __builtin_bit_cast(unsigned, f0) + 0x8000u;
    unsigned a1 = __builtin_bit_cast(unsigned, f1) + 0x8000u;
    return __builtin_amdgcn_perm(a1, a0, 0x07060302u);
#else
    return (unsigned)f2b(f0) | ((unsigned)f2b(f1) << 16);
#endif
}

__device__ __forceinline__ void gl2lds16(const u16* g, u16* l) {
    u16* gn = (u16*)g;
    __builtin_amdgcn_global_load_lds((__attribute__((address_space(1))) void*)gn,
                                     (__attribute__((address_space(3))) void*)l, 16, 0, 0);
}

// ---------------------------------------------------------------------------
// Fused prep: weight transposes (jobs 0..3071) + qkv bias concat (3072..3077)
// + LayerNorm1 rows (3078..4101; 4 rows/block). LN is independent of weights.
// ---------------------------------------------------------------------------
__global__ __launch_bounds__(256) void k_prep(const float* __restrict__ Wq, const float* __restrict__ Wk,
                                              const float* __restrict__ Wv, const float* __restrict__ Wp,
                                              const float* __restrict__ W1, const float* __restrict__ W2,
                                              const float* __restrict__ bq, const float* __restrict__ bk,
                                              const float* __restrict__ bv,
                                              u16* __restrict__ WqkvT, u16* __restrict__ WpT,
                                              u16* __restrict__ W1T, u16* __restrict__ W2T,
                                              float* __restrict__ biasqkv,
                                              const float* __restrict__ x, const float* __restrict__ g1,
                                              const float* __restrict__ be1, u16* __restrict__ xn) {
    int j = blockIdx.x;
    int t = threadIdx.x;
    if (j >= 3078) {                           // LayerNorm1: 4 rows per block
        int wave = t >> 6, lane = t & 63;
        int row = (j - 3078) * 4 + wave;
        const float* xr = x + (size_t)row * DD;
        int c = lane * 8;
        float4 v0 = *(const float4*)(xr + c);
        float4 v1 = *(const float4*)(xr + c + 4);
        float s  = v0.x + v0.y + v0.z + v0.w + v1.x + v1.y + v1.z + v1.w;
        float sq = v0.x*v0.x + v0.y*v0.y + v0.z*v0.z + v0.w*v0.w
                 + v1.x*v1.x + v1.y*v1.y + v1.z*v1.z + v1.w*v1.w;
#pragma unroll
        for (int m = 1; m < 64; m <<= 1) {
            s  += __shfl_xor(s, m);
            sq += __shfl_xor(sq, m);
        }
        float mean = s * (1.0f / DD);
        float var  = sq * (1.0f / DD) - mean * mean;
        float rstd = rsqrtf(var + 1e-5f);
        float4 g0 = *(const float4*)(g1 + c);
        float4 g4 = *(const float4*)(g1 + c + 4);
        float4 b0 = *(const float4*)(be1 + c);
        float4 b4 = *(const float4*)(be1 + c + 4);
        float xv[8] = {v0.x, v0.y, v0.z, v0.w, v1.x, v1.y, v1.z, v1.w};
        float gv[8] = {g0.x, g0.y, g0.z, g0.w, g4.x, g4.y, g4.z, g4.w};
        float bv2[8] = {b0.x, b0.y, b0.z, b0.w, b4.x, b4.y, b4.z, b4.w};
        union { bhalf8 v; u16 u[8]; } pk;
#pragma unroll
        for (int i = 0; i < 8; i++) pk.u[i] = f2b((xv[i] - mean) * rstd * gv[i] + bv2[i]);
        *(bhalf8*)(xn + (size_t)row * DD + c) = pk.v;
        return;
    }
    int tx = t & 31, ty = t >> 5;              // (32,8) mapping
    if (j >= 3072) {                           // bias concat
        int i = (j - 3072) * 256 + ty * 32 + tx;
        biasqkv[i] = (i < 512) ? bq[i] : (i < 1024) ? bk[i - 512] : bv[i - 1024];
        return;
    }
    __shared__ float tile[32][33];
    const float* src; u16* dst; int R, C, tr, tc;
    if (j < 768) {            // Wq/Wk/Wv per-head [512,64] -> [64,512]
        int m = j >> 8, rem = j & 255, h = rem >> 5, tl = rem & 31;
        tr = tl >> 1; tc = tl & 1;
        src = (m == 0 ? Wq : (m == 1 ? Wk : Wv)) + h * 32768;
        dst = WqkvT + m * 262144 + h * 32768;
        R = 512; C = 64;
    } else if (j < 1024) { int tl = j - 768;  tr = tl >> 4; tc = tl & 15; src = Wp; dst = WpT; R = 512;  C = 512;  }
    else if (j < 2048)   { int tl = j - 1024; tr = tl >> 6; tc = tl & 63; src = W1; dst = W1T; R = 512;  C = 2048; }
    else                 { int tl = j - 2048; tr = tl >> 4; tc = tl & 15; src = W2; dst = W2T; R = 2048; C = 512;  }
    int c = tc * 32 + tx;
#pragma unroll
    for (int i = 0; i < 4; i++)
        tile[ty + i * 8][tx] = src[(size_t)(tr * 32 + ty + i * 8) * C + c];
    __syncthreads();
    int r2 = tr * 32 + tx;
#pragma unroll
    for (int i = 0; i < 4; i++)
        dst[(size_t)(tc * 32 + ty + i * 8) * R + r2] = f2b(tile[tx][ty + i * 8]);
}

// ---------------------------------------------------------------------------
// LayerNorm: one wave per 512-col row; fp32 in, bf16 out  (used for LN2)
// ---------------------------------------------------------------------------
__global__ __launch_bounds__(256) void k_layernorm(const float* __restrict__ x,
                                                   const float* __restrict__ g,
                                                   const float* __restrict__ be,
                                                   u16* __restrict__ out) {
    int wave = threadIdx.x >> 6, lane = threadIdx.x & 63;
    int row = blockIdx.x * 4 + wave;
    const float* xr = x + (size_t)row * DD;
    int c = lane * 8;
    float4 v0 = *(const float4*)(xr + c);
    float4 v1 = *(const float4*)(xr + c + 4);
    float s  = v0.x + v0.y + v0.z + v0.w + v1.x + v1.y + v1.z + v1.w;
    float sq = v0.x*v0.x + v0.y*v0.y + v0.z*v0.z + v0.w*v0.w
             + v1.x*v1.x + v1.y*v1.y + v1.z*v1.z + v1.w*v1.w;
#pragma unroll
    for (int m = 1; m < 64; m <<= 1) {
        s  += __shfl_xor(s, m);
        sq += __shfl_xor(sq, m);
    }
    float mean = s * (1.0f / DD);
    float var  = sq * (1.0f / DD) - mean * mean;
    float rstd = rsqrtf(var + 1e-5f);
    float4 g0 = *(const float4*)(g + c);
    float4 g1 = *(const float4*)(g + c + 4);
    float4 b0 = *(const float4*)(be + c);
    float4 b1 = *(const float4*)(be + c + 4);
    float xv[8] = {v0.x, v0.y, v0.z, v0.w, v1.x, v1.y, v1.z, v1.w};
    float gv[8] = {g0.x, g0.y, g0.z, g0.w, g1.x, g1.y, g1.z, g1.w};
    float bv[8] = {b0.x, b0.y, b0.z, b0.w, b1.x, b1.y, b1.z, b1.w};
    union { bhalf8 v; u16 u[8]; } pk;
#pragma unroll
    for (int i = 0; i < 8; i++) pk.u[i] = f2b((xv[i] - mean) * rstd * gv[i] + bv[i]);
    *(bhalf8*)(out + (size_t)row * DD + c) = pk.v;
}

// ---------------------------------------------------------------------------
// bf16 MFMA GEMM, BMxBN tile, BK=64, gl2lds staging (8-row x 64-col 1KB chunks)
// T3 minimum 2-phase (round-6 proven): double-buffered LDS (static As0/As1),
// next tile's global_load_lds issued BEFORE compute, ONE barrier per K-step
// after compute. Requires kLen/64 even (call sites: 8, 8, 8, 32 steps).
// MODE 0: qkv scatter (q scaled by log2e, v transposed [bh,hd,S])
// MODE 1: out fp32 = val + bias + resid
// MODE 2: out bf16 = relu(val + bias)
// ---------------------------------------------------------------------------
template<int BM, int BN, int WR, int WC, int MI, int NI, int MODE>
__global__ __launch_bounds__(256) void k_gemm(const u16* __restrict__ A, const u16* __restrict__ Bt,
                                              const float* __restrict__ bias,
                                              int lda, int ldb, int kLen, int N,
                                              const float* __restrict__ resid,
                                              float* __restrict__ outF, u16* __restrict__ outB,
                                              u16* __restrict__ qd, u16* __restrict__ kd,
                                              u16* __restrict__ vtd) {
    constexpr int WM = MI * 16;
    constexpr int WN = NI * 16;
    static_assert(WR * WM == BM && WC * WN == BN && WR * WC == 4, "cfg");
    constexpr int ACH = BM / 32;          // A staging chunks per wave (8 rows each)
    constexpr int BCH = BN / 32;
    __shared__ u16 As0[BM * 64];
    __shared__ u16 Bs0[BN * 64];
    __shared__ u16 As1[BM * 64];
    __shared__ u16 Bs1[BN * 64];
    int t = threadIdx.x;
    int wave = t >> 6, lane = t & 63, quad = lane >> 4, l16 = lane & 15;
    int wr, wc;
    if (WC == 1)      { wr = wave; wc = 0; }
    else if (WR == 1) { wr = 0;    wc = wave; }
    else              { wr = wave >> 1; wc = wave & 1; }
    int m0 = blockIdx.y * BM, n0 = blockIdx.x * BN;

    f32x4 acc[MI][NI] = {};

    int srow = lane >> 3;                 // 0..7
    int scol = (lane & 7) * 8;
    const u16* Ag = A  + (size_t)(m0 + srow) * lda + scol;
    const u16* Bg = Bt + (size_t)(n0 + srow) * ldb + scol;

    auto stage = [&](u16* Asd, u16* Bsd, int k0) {
#pragma unroll
        for (int c = 0; c < ACH; c++) {
            int ch = wave * ACH + c;
            gl2lds16(Ag + (size_t)(ch * 8) * lda + k0, &Asd[ch * 512]);
        }
#pragma unroll
        for (int c = 0; c < BCH; c++) {
            int ch = wave * BCH + c;
            gl2lds16(Bg + (size_t)(ch * 8) * ldb + k0, &Bsd[ch * 512]);
        }
    };
    auto compute = [&](const u16* Asd, const u16* Bsd) {
#pragma unroll
        for (int h = 0; h < 2; h++) {
            bhalf8 af[MI], bf[NI];
#pragma unroll
            for (int mi = 0; mi < MI; mi++)
                af[mi] = *(const bhalf8*)&Asd[(wr * WM + mi * 16 + l16) * 64 + h * 32 + quad * 8];
#pragma unroll
            for (int ni = 0; ni < NI; ni++)
                bf[ni] = *(const bhalf8*)&Bsd[(wc * WN + ni * 16 + l16) * 64 + h * 32 + quad * 8];
#pragma unroll
            for (int mi = 0; mi < MI; mi++)
#pragma unroll
                for (int ni = 0; ni < NI; ni++)
                    acc[mi][ni] = MFMA16(af[mi], bf[ni], acc[mi][ni]);
        }
    };

    int nt = kLen >> 6;                   // K-steps (even at all call sites)
    stage(As0, Bs0, 0);                   // prologue
    __syncthreads();                      // drain tile 0
    for (int kt = 0; kt < nt; kt += 2) {
        if (kt + 1 < nt) stage(As1, Bs1, (kt + 1) << 6);   // issue next (flies during MFMA)
        compute(As0, Bs0);
        __syncthreads();                  // drain kt+1 loads + protect As0 reuse
        if (kt + 1 < nt) {
            if (kt + 2 < nt) stage(As0, Bs0, (kt + 2) << 6);
            compute(As1, Bs1);
            __syncthreads();
        }
    }

#pragma unroll
    for (int mi = 0; mi < MI; mi++)
#pragma unroll
        for (int ni = 0; ni < NI; ni++) {
            f32x4 a = acc[mi][ni];
            int gc = n0 + wc * WN + ni * 16 + l16;
            int gr0 = m0 + wr * WM + mi * 16 + quad * 4;
            float bsv = bias[gc];
            if (MODE == 0) {
                int mm = gc >> 9, cc = gc & 511;
                int hh = cc >> 6, e = cc & 63;
                int b = gr0 >> 11, s0 = gr0 & 2047;
                if (mm == 2) {
                    u64t pk = 0;
#pragma unroll
                    for (int r = 0; r < 4; r++) pk |= (u64t)f2b(a[r] + bsv) << (16 * r);
                    *(u64t*)&vtd[((size_t)(b * HH + hh) * HD + e) * SS + s0] = pk;
                } else if (mm == 0) {
#pragma unroll
                    for (int r = 0; r < 4; r++)
                        qd[((size_t)(b * HH + hh) * SS + s0 + r) * HD + e] = f2b((a[r] + bsv) * LOG2E);
                } else {
#pragma unroll
                    for (int r = 0; r < 4; r++)
                        kd[((size_t)(b * HH + hh) * SS + s0 + r) * HD + e] = f2b(a[r] + bsv);
                }
            } else if (MODE == 1) {
#pragma unroll
                for (int r = 0; r < 4; r++) {
                    size_t idx = (size_t)(gr0 + r) * N + gc;
                    outF[idx] = a[r] + bsv + resid[idx];
                }
            } else {
#pragma unroll
                for (int r = 0; r < 4; r++)
                    outB[(size_t)(gr0 + r) * N + gc] = f2b(fmaxf(a[r] + bsv, 0.0f));
            }
        }
}

// ---------------------------------------------------------------------------
// Flash attention v6: NO split-KV, fused combine. 512 threads = 8 waves in
// 2 kv-groups; q-tile 64 (16 q-rows/wave, one chunk), kv-tile 128 split
// across groups (nt 0-3/4-7), 16 kv-tiles (full S). Grid (16 bh, 32 qt) =
// 512 blocks -> 2 blocks/CU (same occupancy as v5). K/V LDS double-buffer
// (1 barrier/tile), register prefetch, S^T trick, no-max softmax (q
// pre-scaled by log2e). Group 1 merges into group 0 through dead LDS; the
// block then divides by the full row-sum and writes bf16 oc DIRECTLY —
// eliminates Opart (32MB w + 32MB r), lsum, and the k_combine dispatch.
// Kept: T5 s_setprio, f32x4 row-sum partials, pk2bf pack.
// ---------------------------------------------------------------------------
__global__ __launch_bounds__(512) void k_attention(const u16* __restrict__ q,
                                                   const u16* __restrict__ k,
                                                   const u16* __restrict__ vt,
                                                   u16* __restrict__ oc) {
    __shared__ u16 sm[35840];                 // 71,680 B: 2x (Ks 9216 + Vs 8704 u16)
    u16* Ks0 = sm;                            // [kv][hd] 128*72
    u16* Vs0 = sm + 9216;                     // [hd][kv] 64*136
    u16* Ks1 = sm + 17920;
    u16* Vs1 = sm + 27136;
    float* Ored = (float*)sm;                 // epilogue overlay: 64x64 f32 (16 KB)
    float* Lred = (float*)sm + 4096;          // 64 f32

    int bh = blockIdx.x, qt = blockIdx.y;
    int t = threadIdx.x, wave = t >> 6, lane = t & 63, quad = lane >> 4, l16 = lane & 15;
    int g = wave >> 2, qw = wave & 3;         // kv-group, q-subtile (16 rows)
    const u16* qb = q  + (size_t)bh * SS * HD;
    const u16* kb = k  + (size_t)bh * SS * HD;
    const u16* vb = vt + (size_t)bh * HD * SS;

    // one q-chunk of 16 rows per wave (identical across groups)
    bhalf8 qfa0, qfa1;
    {
        int r0 = qt * 64 + qw * 16 + l16;
        qfa0 = *(const bhalf8*)(qb + (size_t)r0 * HD + quad * 8);
        qfa1 = *(const bhalf8*)(qb + (size_t)r0 * HD + 32 + quad * 8);
    }

    f32x4 oacc[4] = {};
    f32x4 rsa4 = {};

    // staging: 512 threads, 32B each for K and V
    int kr = t >> 2, kc = (t & 3) * 16;       // K: 128 rows x 64 cols
    int vr = t >> 3, vc = (t & 7) * 16;       // V: 64 rows x 128 cols
    const u16* kp = kb + (size_t)kr * HD + kc;
    const u16* vp = vb + (size_t)vr * SS + vc;
    int koff = kr * 72 + kc;
    int voff = vr * 136 + vc;

    bhalf8 kreg[2], vreg[2];
#pragma unroll
    for (int i = 0; i < 2; i++) {             // tile 0 -> regs
        kreg[i] = *(const bhalf8*)(kp + i * 8);
        vreg[i] = *(const bhalf8*)(vp + i * 8);
    }
#pragma unroll
    for (int i = 0; i < 2; i++) {             // tile 0 -> buf0
        *(bhalf8*)(&Ks0[koff] + i * 8) = kreg[i];
        *(bhalf8*)(&Vs0[voff] + i * 8) = vreg[i];
    }
    __syncthreads();
#pragma unroll
    for (int i = 0; i < 2; i++) {             // tile 1 -> regs (always exists)
        kreg[i] = *(const bhalf8*)(kp + (size_t)128 * HD + i * 8);
        vreg[i] = *(const bhalf8*)(vp + 128 + i * 8);
    }

    auto att_step = [&](const u16* Ksb, const u16* Vsb) {
#pragma unroll
        for (int nt2 = 0; nt2 < 4; nt2++) {
            int nt = g * 4 + nt2;
            bhalf8 kf0 = *(const bhalf8*)&Ksb[(nt * 16 + l16) * 72 + quad * 8];
            bhalf8 kf1 = *(const bhalf8*)&Ksb[(nt * 16 + l16) * 72 + 32 + quad * 8];
            // S^T = K·Q^T (C-layout: col=l16=q, row=quad*4+r=kv)
            f32x4 sa = {};
            __builtin_amdgcn_s_setprio(1);
            sa = MFMA16(kf0, qfa0, sa);
            sa = MFMA16(kf1, qfa1, sa);
            __builtin_amdgcn_s_setprio(0);
#if HAVE_K16
            float p0[4];
#pragma unroll
            for (int r = 0; r < 4; r++) p0[r] = EXP2(sa[r]);
#pragma unroll
            for (int r = 0; r < 4; r++) rsa4[r] += p0[r];
            union { bhalf4 v; unsigned w[2]; } pa;
            pa.w[0] = pk2bf(p0[0], p0[1]);
            pa.w[1] = pk2bf(p0[2], p0[3]);
            __builtin_amdgcn_s_setprio(1);
#pragma unroll
            for (int et = 0; et < 4; et++) {
                bhalf4 vf = *(const bhalf4*)&Vsb[(et * 16 + l16) * 136 + nt * 16 + quad * 4];
                oacc[et] = MFMAK16(pa.v, vf, oacc[et]);
            }
            __builtin_amdgcn_s_setprio(0);
#else
            float p0[4];
#pragma unroll
            for (int r = 0; r < 4; r++) {
                p0[r] = EXP2(sa[r]);
                rsa4[r] += p0[r];
            }
            union { bhalf8 v; unsigned w[4]; } pa;
            pa.w[0] = pk2bf(p0[0], p0[1]);
            pa.w[1] = pk2bf(p0[2], p0[3]);
            pa.w[2] = 0; pa.w[3] = 0;
            __builtin_amdgcn_s_setprio(1);
#pragma unroll
            for (int et = 0; et < 4; et++) {
                union { bhalf8 v; bhalf4 h[2]; } vf;
                vf.h[0] = *(const bhalf4*)&Vsb[(et * 16 + l16) * 136 + nt * 16 + quad * 4];
                vf.h[1] = (bhalf4){0, 0, 0, 0};
                oacc[et] = MFMA16(pa.v, vf.v, oacc[et]);
            }
            __builtin_amdgcn_s_setprio(0);
#endif
        }
    };

    // Double-buffered main loop over 16 kv-tiles: one barrier per tile.
    for (int it = 0; it < 16; it += 2) {
        // even: store tile it+1 -> buf1 (writes overlap compute on buf0)
#pragma unroll
        for (int i = 0; i < 2; i++) {
            *(bhalf8*)(&Ks1[koff] + i * 8) = kreg[i];
            *(bhalf8*)(&Vs1[voff] + i * 8) = vreg[i];
        }
        if (it + 2 < 16) {                // prefetch tile it+2 -> regs
            const u16* kn = kp + (size_t)(it + 2) * 128 * HD;
            const u16* vn = vp + (it + 2) * 128;
#pragma unroll
            for (int i = 0; i < 2; i++) {
                kreg[i] = *(const bhalf8*)(kn + i * 8);
                vreg[i] = *(const bhalf8*)(vn + i * 8);
            }
        }
        att_step(Ks0, Vs0);               // compute tile it
        __syncthreads();
        // odd: store tile it+2 -> buf0, compute tile it+1 from buf1
        if (it + 2 < 16) {
#pragma unroll
            for (int i = 0; i < 2; i++) {
                *(bhalf8*)(&Ks0[koff] + i * 8) = kreg[i];
                *(bhalf8*)(&Vs0[voff] + i * 8) = vreg[i];
            }
            if (it + 3 < 16) {            // prefetch tile it+3 -> regs
                const u16* kn = kp + (size_t)(it + 3) * 128 * HD;
                const u16* vn = vp + (it + 3) * 128;
#pragma unroll
                for (int i = 0; i < 2; i++) {
                    kreg[i] = *(const bhalf8*)(kn + i * 8);
                    vreg[i] = *(const bhalf8*)(vn + i * 8);
                }
            }
        }
        att_step(Ks1, Vs1);               // compute tile it+1
        __syncthreads();
    }

    float rsa = (rsa4[0] + rsa4[1]) + (rsa4[2] + rsa4[3]);
    rsa += __shfl_xor(rsa, 16); rsa += __shfl_xor(rsa, 32);
    // now lane (any quad, l16) holds this group's row-sum for q-row qw*16+l16

    // all K/V LDS dead (loop ended with barrier); overlay buf0 as Ored/Lred
    if (g == 1) {
#pragma unroll
        for (int et = 0; et < 4; et++)
#pragma unroll
            for (int r = 0; r < 4; r++)
                Ored[(qw * 16 + quad * 4 + r) * 64 + et * 16 + l16] = oacc[et][r];
        if (quad == 0) Lred[qw * 16 + l16] = rsa;
    }
    __syncthreads();
    if (g == 0) {
        float inv = 1.0f / (rsa + Lred[qw * 16 + l16]);   // full row-sum, row qw*16+l16
        int b = bh >> 3, h = bh & 7;
#pragma unroll
        for (int r = 0; r < 4; r++) {
            float li = __shfl(inv, quad * 4 + r);          // inv for q-row qw*16+quad*4+r
            int s = qt * 64 + qw * 16 + quad * 4 + r;
            u16* orow = oc + ((size_t)b * SS + s) * DD + h * HD;
#pragma unroll
            for (int et = 0; et < 4; et++) {
                float v = oacc[et][r]
                        + Ored[(qw * 16 + quad * 4 + r) * 64 + et * 16 + l16];
                orow[et * 16 + l16] = f2b(v * li);
            }
        }
    }
}

// ---------------------------------------------------------------------------
extern "C" void kernel_launch(void* const* d_in, const int* in_sizes, int n_in,
                              void* d_out, int out_size, void* d_ws, size_t ws_size,
                              hipStream_t stream) {
    const float* x   = (const float*)d_in[0];
    const float* Wq  = (const float*)d_in[1];
    const float* bq  = (const float*)d_in[2];
    const float* Wk  = (const float*)d_in[3];
    const float* bk  = (const float*)d_in[4];
    const float* Wv  = (const float*)d_in[5];
    const float* bv  = (const float*)d_in[6];
    const float* Wp  = (const float*)d_in[7];
    const float* bp  = (const float*)d_in[8];
    const float* W1  = (const float*)d_in[9];
    const float* b1  = (const float*)d_in[10];
    const float* W2  = (const float*)d_in[11];
    const float* b2  = (const float*)d_in[12];
    const float* g1  = (const float*)d_in[13];
    const float* be1 = (const float*)d_in[14];
    const float* g2  = (const float*)d_in[15];
    const float* be2 = (const float*)d_in[16];

    char* ws = (char*)d_ws;
    u16*   WqkvT   = (u16*)(ws + 0);                    // 1,572,864
    u16*   WpT     = (u16*)(ws + 1572864);              //   524,288
    u16*   W1T     = (u16*)(ws + 2097152);              // 2,097,152
    u16*   W2T     = (u16*)(ws + 4194304);              // 2,097,152
    float* biasqkv = (float*)(ws + 6291456);            // 6,144
    u16*   xn      = (u16*)(ws + 6297600);              // 4,194,304
    u16*   qB      = (u16*)(ws + 10491904);             // 4,194,304
    u16*   kB      = (u16*)(ws + 14686208);             // 4,194,304
    u16*   vTb     = (u16*)(ws + 18880512);             // 4,194,304  [bh,hd,S]
    u16*   oc      = (u16*)(ws + 23074816);             // 4,194,304
    float* x1      = (float*)(ws + 27269120);           // 8,388,608
    u16*   xn2     = (u16*)(ws + 35657728);             // 4,194,304
    u16*   hbuf    = (u16*)(ws + 39852032);             // 16,777,216 (MLP1 out)

    // prep (weights + bias concat) fused with LN1
    k_prep<<<4102, 256, 0, stream>>>(Wq, Wk, Wv, Wp, W1, W2, bq, bk, bv,
                                     WqkvT, WpT, W1T, W2T, biasqkv,
                                     x, g1, be1, xn);
    // QKV: 128x128 BK=64 dbuf-prefetch, grid 384
    k_gemm<128, 128, 2, 2, 4, 4, 0><<<dim3(12, 32), 256, 0, stream>>>(
        xn, WqkvT, biasqkv, 512, 512, 512, 1536, nullptr, nullptr, nullptr, qB, kB, vTb);
    // attention v6: no split-KV, fused combine; grid (16 bh, 32 qt) = 512
    k_attention<<<dim3(16, 32), 512, 0, stream>>>(qB, kB, vTb, oc);
    // proj + residual: 64x64 BK=64 dbuf-prefetch, grid 512
    k_gemm<64, 64, 2, 2, 2, 2, 1><<<dim3(8, 64), 256, 0, stream>>>(
        oc, WpT, bp, 512, 512, 512, 512, x, x1, nullptr, nullptr, nullptr, nullptr);
    k_layernorm<<<NT / 4, 256, 0, stream>>>(x1, g2, be2, xn2);
    // MLP1: 128x128 BK=64 dbuf-prefetch, grid 512
    k_gemm<128, 128, 2, 2, 4, 4, 2><<<dim3(16, 32), 256, 0, stream>>>(
        xn2, W1T, b1, 512, 512, 512, 2048, nullptr, nullptr, hbuf, nullptr, nullptr, nullptr);
    // MLP2 + residual: 64x64 BK=64 dbuf-prefetch, K=2048, grid 512
    // (round-7 falsified 128x64 @ 1 block/CU: 2 blocks/CU wins — keep 64x64)
    k_gemm<64, 64, 2, 2, 2, 2, 1><<<dim3(8, 64), 256, 0, stream>>>(
        hbuf, W2T, b2, 2048, 2048, 2048, 512, x1, (float*)d_out, nullptr, nullptr, nullptr, nullptr);
}

// Round 11
// 192.407 us; speedup vs baseline: 1.0382x; 1.0080x over previous
//
#include <hip/hip_runtime.h>
#include <hip/hip_bf16.h>

typedef unsigned short u16;
typedef unsigned long long u64t;
typedef __attribute__((ext_vector_type(8))) short bhalf8;   // 8 x bf16 (4 VGPRs)
typedef __attribute__((ext_vector_type(4))) short bhalf4;   // 4 x bf16 (2 VGPRs)
typedef __attribute__((ext_vector_type(4))) float f32x4;    // MFMA accumulator

#define MFMA16(a, b, c) __builtin_amdgcn_mfma_f32_16x16x32_bf16((a), (b), (c), 0, 0, 0)

#if __has_builtin(__builtin_amdgcn_mfma_f32_16x16x16bf16_1k)
#define HAVE_K16 1
#define MFMAK16(a, b, c) __builtin_amdgcn_mfma_f32_16x16x16bf16_1k((a), (b), (c), 0, 0, 0)
#elif __has_builtin(__builtin_amdgcn_mfma_f32_16x16x16_bf16)
#define HAVE_K16 1
#define MFMAK16(a, b, c) __builtin_amdgcn_mfma_f32_16x16x16_bf16((a), (b), (c), 0, 0, 0)
#else
#define HAVE_K16 0
#endif

#if __has_builtin(__builtin_amdgcn_perm)
#define HAVE_PERM 1
#else
#define HAVE_PERM 0
#endif

#define BB 2
#define SS 2048
#define DD 512
#define HH 8
#define HD 64
#define NT (BB * SS)
#define LOG2E 1.44269504f

#if __has_builtin(__builtin_amdgcn_exp2f)
#define EXP2(x) __builtin_amdgcn_exp2f(x)
#else
#define EXP2(x) exp2f(x)
#endif

__device__ __forceinline__ u16 f2b(float f) {
    unsigned u = __builtin_bit_cast(unsigned, f);
    unsigned r = (u + 0x7fffu + ((u >> 16) & 1u)) >> 16;
    return (u16)r;
}

// Pack two fp32 -> two bf16 (round-half-up) in one dword: 2x v_add + 1x v_perm.
// Result: low16 = bf16(f0), high16 = bf16(f1).
__device__ __forceinline__ unsigned pk2bf(float f0, float f1) {
#if HAVE_PERM
    unsigned a0 = __builtin_bit_cast(unsigned, f0) + 0x8000u;
    unsigned a1 = __builtin_bit_cast(unsigned, f1) + 0x8000u;
    return __builtin_amdgcn_perm(a1, a0, 0x07060302u);
#else
    return (unsigned)f2b(f0) | ((unsigned)f2b(f1) << 16);
#endif
}

__device__ __forceinline__ void gl2lds16(const u16* g, u16* l) {
    u16* gn = (u16*)g;
    __builtin_amdgcn_global_load_lds((__attribute__((address_space(1))) void*)gn,
                                     (__attribute__((address_space(3))) void*)l, 16, 0, 0);
}

// ---------------------------------------------------------------------------
// Fused prep: weight transposes (jobs 0..3071) + qkv bias concat (3072..3077)
// + LayerNorm1 rows (3078..4101; 4 rows/block). LN is independent of weights.
// ---------------------------------------------------------------------------
__global__ __launch_bounds__(256) void k_prep(const float* __restrict__ Wq, const float* __restrict__ Wk,
                                              const float* __restrict__ Wv, const float* __restrict__ Wp,
                                              const float* __restrict__ W1, const float* __restrict__ W2,
                                              const float* __restrict__ bq, const float* __restrict__ bk,
                                              const float* __restrict__ bv,
                                              u16* __restrict__ WqkvT, u16* __restrict__ WpT,
                                              u16* __restrict__ W1T, u16* __restrict__ W2T,
                                              float* __restrict__ biasqkv,
                                              const float* __restrict__ x, const float* __restrict__ g1,
                                              const float* __restrict__ be1, u16* __restrict__ xn) {
    int j = blockIdx.x;
    int t = threadIdx.x;
    if (j >= 3078) {                           // LayerNorm1: 4 rows per block
        int wave = t >> 6, lane = t & 63;
        int row = (j - 3078) * 4 + wave;
        const float* xr = x + (size_t)row * DD;
        int c = lane * 8;
        float4 v0 = *(const float4*)(xr + c);
        float4 v1 = *(const float4*)(xr + c + 4);
        float s  = v0.x + v0.y + v0.z + v0.w + v1.x + v1.y + v1.z + v1.w;
        float sq = v0.x*v0.x + v0.y*v0.y + v0.z*v0.z + v0.w*v0.w
                 + v1.x*v1.x + v1.y*v1.y + v1.z*v1.z + v1.w*v1.w;
#pragma unroll
        for (int m = 1; m < 64; m <<= 1) {
            s  += __shfl_xor(s, m);
            sq += __shfl_xor(sq, m);
        }
        float mean = s * (1.0f / DD);
        float var  = sq * (1.0f / DD) - mean * mean;
        float rstd = rsqrtf(var + 1e-5f);
        float4 g0 = *(const float4*)(g1 + c);
        float4 g4 = *(const float4*)(g1 + c + 4);
        float4 b0 = *(const float4*)(be1 + c);
        float4 b4 = *(const float4*)(be1 + c + 4);
        float xv[8] = {v0.x, v0.y, v0.z, v0.w, v1.x, v1.y, v1.z, v1.w};
        float gv[8] = {g0.x, g0.y, g0.z, g0.w, g4.x, g4.y, g4.z, g4.w};
        float bv2[8] = {b0.x, b0.y, b0.z, b0.w, b4.x, b4.y, b4.z, b4.w};
        union { bhalf8 v; u16 u[8]; } pk;
#pragma unroll
        for (int i = 0; i < 8; i++) pk.u[i] = f2b((xv[i] - mean) * rstd * gv[i] + bv2[i]);
        *(bhalf8*)(xn + (size_t)row * DD + c) = pk.v;
        return;
    }
    int tx = t & 31, ty = t >> 5;              // (32,8) mapping
    if (j >= 3072) {                           // bias concat
        int i = (j - 3072) * 256 + ty * 32 + tx;
        biasqkv[i] = (i < 512) ? bq[i] : (i < 1024) ? bk[i - 512] : bv[i - 1024];
        return;
    }
    __shared__ float tile[32][33];
    const float* src; u16* dst; int R, C, tr, tc;
    if (j < 768) {            // Wq/Wk/Wv per-head [512,64] -> [64,512]
        int m = j >> 8, rem = j & 255, h = rem >> 5, tl = rem & 31;
        tr = tl >> 1; tc = tl & 1;
        src = (m == 0 ? Wq : (m == 1 ? Wk : Wv)) + h * 32768;
        dst = WqkvT + m * 262144 + h * 32768;
        R = 512; C = 64;
    } else if (j < 1024) { int tl = j - 768;  tr = tl >> 4; tc = tl & 15; src = Wp; dst = WpT; R = 512;  C = 512;  }
    else if (j < 2048)   { int tl = j - 1024; tr = tl >> 6; tc = tl & 63; src = W1; dst = W1T; R = 512;  C = 2048; }
    else                 { int tl = j - 2048; tr = tl >> 4; tc = tl & 15; src = W2; dst = W2T; R = 2048; C = 512;  }
    int c = tc * 32 + tx;
#pragma unroll
    for (int i = 0; i < 4; i++)
        tile[ty + i * 8][tx] = src[(size_t)(tr * 32 + ty + i * 8) * C + c];
    __syncthreads();
    int r2 = tr * 32 + tx;
#pragma unroll
    for (int i = 0; i < 4; i++)
        dst[(size_t)(tc * 32 + ty + i * 8) * R + r2] = f2b(tile[tx][ty + i * 8]);
}

// ---------------------------------------------------------------------------
// LayerNorm: one wave per 512-col row; fp32 in, bf16 out  (used for LN2)
// ---------------------------------------------------------------------------
__global__ __launch_bounds__(256) void k_layernorm(const float* __restrict__ x,
                                                   const float* __restrict__ g,
                                                   const float* __restrict__ be,
                                                   u16* __restrict__ out) {
    int wave = threadIdx.x >> 6, lane = threadIdx.x & 63;
    int row = blockIdx.x * 4 + wave;
    const float* xr = x + (size_t)row * DD;
    int c = lane * 8;
    float4 v0 = *(const float4*)(xr + c);
    float4 v1 = *(const float4*)(xr + c + 4);
    float s  = v0.x + v0.y + v0.z + v0.w + v1.x + v1.y + v1.z + v1.w;
    float sq = v0.x*v0.x + v0.y*v0.y + v0.z*v0.z + v0.w*v0.w
             + v1.x*v1.x + v1.y*v1.y + v1.z*v1.z + v1.w*v1.w;
#pragma unroll
    for (int m = 1; m < 64; m <<= 1) {
        s  += __shfl_xor(s, m);
        sq += __shfl_xor(sq, m);
    }
    float mean = s * (1.0f / DD);
    float var  = sq * (1.0f / DD) - mean * mean;
    float rstd = rsqrtf(var + 1e-5f);
    float4 g0 = *(const float4*)(g + c);
    float4 g1 = *(const float4*)(g + c + 4);
    float4 b0 = *(const float4*)(be + c);
    float4 b1 = *(const float4*)(be + c + 4);
    float xv[8] = {v0.x, v0.y, v0.z, v0.w, v1.x, v1.y, v1.z, v1.w};
    float gv[8] = {g0.x, g0.y, g0.z, g0.w, g1.x, g1.y, g1.z, g1.w};
    float bv[8] = {b0.x, b0.y, b0.z, b0.w, b1.x, b1.y, b1.z, b1.w};
    union { bhalf8 v; u16 u[8]; } pk;
#pragma unroll
    for (int i = 0; i < 8; i++) pk.u[i] = f2b((xv[i] - mean) * rstd * gv[i] + bv[i]);
    *(bhalf8*)(out + (size_t)row * DD + c) = pk.v;
}

// ---------------------------------------------------------------------------
// bf16 MFMA GEMM, BMxBN tile, BK=64, gl2lds staging (8-row x 64-col 1KB chunks)
// T3 minimum 2-phase (round-6 proven): double-buffered LDS (static As0/As1),
// next tile's global_load_lds issued BEFORE compute, ONE barrier per K-step
// after compute. Requires kLen/64 even (call sites: 8, 8, 8, 32 steps).
// MODE 0: qkv scatter (q scaled by log2e, v transposed [bh,hd,S])
// MODE 1: out fp32 = val + bias + resid
// MODE 2: out bf16 = relu(val + bias)
// ---------------------------------------------------------------------------
template<int BM, int BN, int WR, int WC, int MI, int NI, int MODE>
__global__ __launch_bounds__(256) void k_gemm(const u16* __restrict__ A, const u16* __restrict__ Bt,
                                              const float* __restrict__ bias,
                                              int lda, int ldb, int kLen, int N,
                                              const float* __restrict__ resid,
                                              float* __restrict__ outF, u16* __restrict__ outB,
                                              u16* __restrict__ qd, u16* __restrict__ kd,
                                              u16* __restrict__ vtd) {
    constexpr int WM = MI * 16;
    constexpr int WN = NI * 16;
    static_assert(WR * WM == BM && WC * WN == BN && WR * WC == 4, "cfg");
    constexpr int ACH = BM / 32;          // A staging chunks per wave (8 rows each)
    constexpr int BCH = BN / 32;
    __shared__ u16 As0[BM * 64];
    __shared__ u16 Bs0[BN * 64];
    __shared__ u16 As1[BM * 64];
    __shared__ u16 Bs1[BN * 64];
    int t = threadIdx.x;
    int wave = t >> 6, lane = t & 63, quad = lane >> 4, l16 = lane & 15;
    int wr, wc;
    if (WC == 1)      { wr = wave; wc = 0; }
    else if (WR == 1) { wr = 0;    wc = wave; }
    else              { wr = wave >> 1; wc = wave & 1; }
    int m0 = blockIdx.y * BM, n0 = blockIdx.x * BN;

    f32x4 acc[MI][NI] = {};

    int srow = lane >> 3;                 // 0..7
    int scol = (lane & 7) * 8;
    const u16* Ag = A  + (size_t)(m0 + srow) * lda + scol;
    const u16* Bg = Bt + (size_t)(n0 + srow) * ldb + scol;

    auto stage = [&](u16* Asd, u16* Bsd, int k0) {
#pragma unroll
        for (int c = 0; c < ACH; c++) {
            int ch = wave * ACH + c;
            gl2lds16(Ag + (size_t)(ch * 8) * lda + k0, &Asd[ch * 512]);
        }
#pragma unroll
        for (int c = 0; c < BCH; c++) {
            int ch = wave * BCH + c;
            gl2lds16(Bg + (size_t)(ch * 8) * ldb + k0, &Bsd[ch * 512]);
        }
    };
    auto compute = [&](const u16* Asd, const u16* Bsd) {
#pragma unroll
        for (int h = 0; h < 2; h++) {
            bhalf8 af[MI], bf[NI];
#pragma unroll
            for (int mi = 0; mi < MI; mi++)
                af[mi] = *(const bhalf8*)&Asd[(wr * WM + mi * 16 + l16) * 64 + h * 32 + quad * 8];
#pragma unroll
            for (int ni = 0; ni < NI; ni++)
                bf[ni] = *(const bhalf8*)&Bsd[(wc * WN + ni * 16 + l16) * 64 + h * 32 + quad * 8];
#pragma unroll
            for (int mi = 0; mi < MI; mi++)
#pragma unroll
                for (int ni = 0; ni < NI; ni++)
                    acc[mi][ni] = MFMA16(af[mi], bf[ni], acc[mi][ni]);
        }
    };

    int nt = kLen >> 6;                   // K-steps (even at all call sites)
    stage(As0, Bs0, 0);                   // prologue
    __syncthreads();                      // drain tile 0
    for (int kt = 0; kt < nt; kt += 2) {
        if (kt + 1 < nt) stage(As1, Bs1, (kt + 1) << 6);   // issue next (flies during MFMA)
        compute(As0, Bs0);
        __syncthreads();                  // drain kt+1 loads + protect As0 reuse
        if (kt + 1 < nt) {
            if (kt + 2 < nt) stage(As0, Bs0, (kt + 2) << 6);
            compute(As1, Bs1);
            __syncthreads();
        }
    }

#pragma unroll
    for (int mi = 0; mi < MI; mi++)
#pragma unroll
        for (int ni = 0; ni < NI; ni++) {
            f32x4 a = acc[mi][ni];
            int gc = n0 + wc * WN + ni * 16 + l16;
            int gr0 = m0 + wr * WM + mi * 16 + quad * 4;
            float bsv = bias[gc];
            if (MODE == 0) {
                int mm = gc >> 9, cc = gc & 511;
                int hh = cc >> 6, e = cc & 63;
                int b = gr0 >> 11, s0 = gr0 & 2047;
                if (mm == 2) {
                    u64t pk = 0;
#pragma unroll
                    for (int r = 0; r < 4; r++) pk |= (u64t)f2b(a[r] + bsv) << (16 * r);
                    *(u64t*)&vtd[((size_t)(b * HH + hh) * HD + e) * SS + s0] = pk;
                } else if (mm == 0) {
#pragma unroll
                    for (int r = 0; r < 4; r++)
                        qd[((size_t)(b * HH + hh) * SS + s0 + r) * HD + e] = f2b((a[r] + bsv) * LOG2E);
                } else {
#pragma unroll
                    for (int r = 0; r < 4; r++)
                        kd[((size_t)(b * HH + hh) * SS + s0 + r) * HD + e] = f2b(a[r] + bsv);
                }
            } else if (MODE == 1) {
#pragma unroll
                for (int r = 0; r < 4; r++) {
                    size_t idx = (size_t)(gr0 + r) * N + gc;
                    outF[idx] = a[r] + bsv + resid[idx];
                }
            } else {
#pragma unroll
                for (int r = 0; r < 4; r++)
                    outB[(size_t)(gr0 + r) * N + gc] = f2b(fmaxf(a[r] + bsv, 0.0f));
            }
        }
}

// ---------------------------------------------------------------------------
// Flash attention v6: NO split-KV, fused combine. 512 threads = 8 waves in
// 2 kv-groups; q-tile 64 (16 q-rows/wave, one chunk), kv-tile 128 split
// across groups (nt 0-3/4-7), 16 kv-tiles (full S). Grid (16 bh, 32 qt) =
// 512 blocks -> 2 blocks/CU. K/V LDS double-buffer (1 barrier/tile),
// register prefetch, S^T trick, no-max softmax (q pre-scaled by log2e).
// Group 1 merges into group 0 through dead LDS; block divides by full
// row-sum and writes bf16 oc directly (no Opart/lsum/combine).
// Kept: T5 s_setprio, f32x4 row-sum partials, pk2bf pack.
// ---------------------------------------------------------------------------
__global__ __launch_bounds__(512) void k_attention(const u16* __restrict__ q,
                                                   const u16* __restrict__ k,
                                                   const u16* __restrict__ vt,
                                                   u16* __restrict__ oc) {
    __shared__ u16 sm[35840];                 // 71,680 B: 2x (Ks 9216 + Vs 8704 u16)
    u16* Ks0 = sm;                            // [kv][hd] 128*72
    u16* Vs0 = sm + 9216;                     // [hd][kv] 64*136
    u16* Ks1 = sm + 17920;
    u16* Vs1 = sm + 27136;
    float* Ored = (float*)sm;                 // epilogue overlay: 64x64 f32 (16 KB)
    float* Lred = (float*)sm + 4096;          // 64 f32

    int bh = blockIdx.x, qt = blockIdx.y;
    int t = threadIdx.x, wave = t >> 6, lane = t & 63, quad = lane >> 4, l16 = lane & 15;
    int g = wave >> 2, qw = wave & 3;         // kv-group, q-subtile (16 rows)
    const u16* qb = q  + (size_t)bh * SS * HD;
    const u16* kb = k  + (size_t)bh * SS * HD;
    const u16* vb = vt + (size_t)bh * HD * SS;

    // one q-chunk of 16 rows per wave (identical across groups)
    bhalf8 qfa0, qfa1;
    {
        int r0 = qt * 64 + qw * 16 + l16;
        qfa0 = *(const bhalf8*)(qb + (size_t)r0 * HD + quad * 8);
        qfa1 = *(const bhalf8*)(qb + (size_t)r0 * HD + 32 + quad * 8);
    }

    f32x4 oacc[4] = {};
    f32x4 rsa4 = {};

    // staging: 512 threads, 32B each for K and V
    int kr = t >> 2, kc = (t & 3) * 16;       // K: 128 rows x 64 cols
    int vr = t >> 3, vc = (t & 7) * 16;       // V: 64 rows x 128 cols
    const u16* kp = kb + (size_t)kr * HD + kc;
    const u16* vp = vb + (size_t)vr * SS + vc;
    int koff = kr * 72 + kc;
    int voff = vr * 136 + vc;

    bhalf8 kreg[2], vreg[2];
#pragma unroll
    for (int i = 0; i < 2; i++) {             // tile 0 -> regs
        kreg[i] = *(const bhalf8*)(kp + i * 8);
        vreg[i] = *(const bhalf8*)(vp + i * 8);
    }
#pragma unroll
    for (int i = 0; i < 2; i++) {             // tile 0 -> buf0
        *(bhalf8*)(&Ks0[koff] + i * 8) = kreg[i];
        *(bhalf8*)(&Vs0[voff] + i * 8) = vreg[i];
    }
    __syncthreads();
#pragma unroll
    for (int i = 0; i < 2; i++) {             // tile 1 -> regs (always exists)
        kreg[i] = *(const bhalf8*)(kp + (size_t)128 * HD + i * 8);
        vreg[i] = *(const bhalf8*)(vp + 128 + i * 8);
    }

    auto att_step = [&](const u16* Ksb, const u16* Vsb) {
#pragma unroll
        for (int nt2 = 0; nt2 < 4; nt2++) {
            int nt = g * 4 + nt2;
            bhalf8 kf0 = *(const bhalf8*)&Ksb[(nt * 16 + l16) * 72 + quad * 8];
            bhalf8 kf1 = *(const bhalf8*)&Ksb[(nt * 16 + l16) * 72 + 32 + quad * 8];
            // S^T = K·Q^T (C-layout: col=l16=q, row=quad*4+r=kv)
            f32x4 sa = {};
            __builtin_amdgcn_s_setprio(1);
            sa = MFMA16(kf0, qfa0, sa);
            sa = MFMA16(kf1, qfa1, sa);
            __builtin_amdgcn_s_setprio(0);
#if HAVE_K16
            float p0[4];
#pragma unroll
            for (int r = 0; r < 4; r++) p0[r] = EXP2(sa[r]);
#pragma unroll
            for (int r = 0; r < 4; r++) rsa4[r] += p0[r];
            union { bhalf4 v; unsigned w[2]; } pa;
            pa.w[0] = pk2bf(p0[0], p0[1]);
            pa.w[1] = pk2bf(p0[2], p0[3]);
            __builtin_amdgcn_s_setprio(1);
#pragma unroll
            for (int et = 0; et < 4; et++) {
                bhalf4 vf = *(const bhalf4*)&Vsb[(et * 16 + l16) * 136 + nt * 16 + quad * 4];
                oacc[et] = MFMAK16(pa.v, vf, oacc[et]);
            }
            __builtin_amdgcn_s_setprio(0);
#else
            float p0[4];
#pragma unroll
            for (int r = 0; r < 4; r++) {
                p0[r] = EXP2(sa[r]);
                rsa4[r] += p0[r];
            }
            union { bhalf8 v; unsigned w[4]; } pa;
            pa.w[0] = pk2bf(p0[0], p0[1]);
            pa.w[1] = pk2bf(p0[2], p0[3]);
            pa.w[2] = 0; pa.w[3] = 0;
            __builtin_amdgcn_s_setprio(1);
#pragma unroll
            for (int et = 0; et < 4; et++) {
                union { bhalf8 v; bhalf4 h[2]; } vf;
                vf.h[0] = *(const bhalf4*)&Vsb[(et * 16 + l16) * 136 + nt * 16 + quad * 4];
                vf.h[1] = (bhalf4){0, 0, 0, 0};
                oacc[et] = MFMA16(pa.v, vf.v, oacc[et]);
            }
            __builtin_amdgcn_s_setprio(0);
#endif
        }
    };

    // Double-buffered main loop over 16 kv-tiles: one barrier per tile.
    for (int it = 0; it < 16; it += 2) {
        // even: store tile it+1 -> buf1 (writes overlap compute on buf0)
#pragma unroll
        for (int i = 0; i < 2; i++) {
            *(bhalf8*)(&Ks1[koff] + i * 8) = kreg[i];
            *(bhalf8*)(&Vs1[voff] + i * 8) = vreg[i];
        }
        if (it + 2 < 16) {                // prefetch tile it+2 -> regs
            const u16* kn = kp + (size_t)(it + 2) * 128 * HD;
            const u16* vn = vp + (it + 2) * 128;
#pragma unroll
            for (int i = 0; i < 2; i++) {
                kreg[i] = *(const bhalf8*)(kn + i * 8);
                vreg[i] = *(const bhalf8*)(vn + i * 8);
            }
        }
        att_step(Ks0, Vs0);               // compute tile it
        __syncthreads();
        // odd: store tile it+2 -> buf0, compute tile it+1 from buf1
        if (it + 2 < 16) {
#pragma unroll
            for (int i = 0; i < 2; i++) {
                *(bhalf8*)(&Ks0[koff] + i * 8) = kreg[i];
                *(bhalf8*)(&Vs0[voff] + i * 8) = vreg[i];
            }
            if (it + 3 < 16) {            // prefetch tile it+3 -> regs
                const u16* kn = kp + (size_t)(it + 3) * 128 * HD;
                const u16* vn = vp + (it + 3) * 128;
#pragma unroll
                for (int i = 0; i < 2; i++) {
                    kreg[i] = *(const bhalf8*)(kn + i * 8);
                    vreg[i] = *(const bhalf8*)(vn + i * 8);
                }
            }
        }
        att_step(Ks1, Vs1);               // compute tile it+1
        __syncthreads();
    }

    float rsa = (rsa4[0] + rsa4[1]) + (rsa4[2] + rsa4[3]);
    rsa += __shfl_xor(rsa, 16); rsa += __shfl_xor(rsa, 32);
    // now lane (any quad, l16) holds this group's row-sum for q-row qw*16+l16

    // all K/V LDS dead (loop ended with barrier); overlay buf0 as Ored/Lred
    if (g == 1) {
#pragma unroll
        for (int et = 0; et < 4; et++)
#pragma unroll
            for (int r = 0; r < 4; r++)
                Ored[(qw * 16 + quad * 4 + r) * 64 + et * 16 + l16] = oacc[et][r];
        if (quad == 0) Lred[qw * 16 + l16] = rsa;
    }
    __syncthreads();
    if (g == 0) {
        float inv = 1.0f / (rsa + Lred[qw * 16 + l16]);   // full row-sum, row qw*16+l16
        int b = bh >> 3, h = bh & 7;
#pragma unroll
        for (int r = 0; r < 4; r++) {
            float li = __shfl(inv, quad * 4 + r);          // inv for q-row qw*16+quad*4+r
            int s = qt * 64 + qw * 16 + quad * 4 + r;
            u16* orow = oc + ((size_t)b * SS + s) * DD + h * HD;
#pragma unroll
            for (int et = 0; et < 4; et++) {
                float v = oacc[et][r]
                        + Ored[(qw * 16 + quad * 4 + r) * 64 + et * 16 + l16];
                orow[et * 16 + l16] = f2b(v * li);
            }
        }
    }
}

// ---------------------------------------------------------------------------
extern "C" void kernel_launch(void* const* d_in, const int* in_sizes, int n_in,
                              void* d_out, int out_size, void* d_ws, size_t ws_size,
                              hipStream_t stream) {
    const float* x   = (const float*)d_in[0];
    const float* Wq  = (const float*)d_in[1];
    const float* bq  = (const float*)d_in[2];
    const float* Wk  = (const float*)d_in[3];
    const float* bk  = (const float*)d_in[4];
    const float* Wv  = (const float*)d_in[5];
    const float* bv  = (const float*)d_in[6];
    const float* Wp  = (const float*)d_in[7];
    const float* bp  = (const float*)d_in[8];
    const float* W1  = (const float*)d_in[9];
    const float* b1  = (const float*)d_in[10];
    const float* W2  = (const float*)d_in[11];
    const float* b2  = (const float*)d_in[12];
    const float* g1  = (const float*)d_in[13];
    const float* be1 = (const float*)d_in[14];
    const float* g2  = (const float*)d_in[15];
    const float* be2 = (const float*)d_in[16];

    char* ws = (char*)d_ws;
    u16*   WqkvT   = (u16*)(ws + 0);                    // 1,572,864
    u16*   WpT     = (u16*)(ws + 1572864);              //   524,288
    u16*   W1T     = (u16*)(ws + 2097152);              // 2,097,152
    u16*   W2T     = (u16*)(ws + 4194304);              // 2,097,152
    float* biasqkv = (float*)(ws + 6291456);            // 6,144
    u16*   xn      = (u16*)(ws + 6297600);              // 4,194,304
    u16*   qB      = (u16*)(ws + 10491904);             // 4,194,304
    u16*   kB      = (u16*)(ws + 14686208);             // 4,194,304
    u16*   vTb     = (u16*)(ws + 18880512);             // 4,194,304  [bh,hd,S]
    u16*   oc      = (u16*)(ws + 23074816);             // 4,194,304
    float* x1      = (float*)(ws + 27269120);           // 8,388,608
    u16*   xn2     = (u16*)(ws + 35657728);             // 4,194,304
    u16*   hbuf    = (u16*)(ws + 39852032);             // 16,777,216 (MLP1 out)

    // prep (weights + bias concat) fused with LN1
    k_prep<<<4102, 256, 0, stream>>>(Wq, Wk, Wv, Wp, W1, W2, bq, bk, bv,
                                     WqkvT, WpT, W1T, W2T, biasqkv,
                                     x, g1, be1, xn);
    // QKV: 64x128 tile, grid (12,64) = 768 blocks @ 3 blocks/CU — perfectly
    // balanced across 256 CUs (old 128x128 grid 384 left half the CUs with
    // 1 block while the other half carried 2). LDS 48KB dbuf; bit-identical
    // per-output K-order.
    k_gemm<64, 128, 2, 2, 2, 4, 0><<<dim3(12, 64), 256, 0, stream>>>(
        xn, WqkvT, biasqkv, 512, 512, 512, 1536, nullptr, nullptr, nullptr, qB, kB, vTb);
    // attention v6: no split-KV, fused combine; grid (16 bh, 32 qt) = 512
    k_attention<<<dim3(16, 32), 512, 0, stream>>>(qB, kB, vTb, oc);
    // proj + residual: 64x64 BK=64 dbuf-prefetch, grid 512
    k_gemm<64, 64, 2, 2, 2, 2, 1><<<dim3(8, 64), 256, 0, stream>>>(
        oc, WpT, bp, 512, 512, 512, 512, x, x1, nullptr, nullptr, nullptr, nullptr);
    k_layernorm<<<NT / 4, 256, 0, stream>>>(x1, g2, be2, xn2);
    // MLP1: 128x128 BK=64 dbuf-prefetch, grid 512
    k_gemm<128, 128, 2, 2, 4, 4, 2><<<dim3(16, 32), 256, 0, stream>>>(
        xn2, W1T, b1, 512, 512, 512, 2048, nullptr, nullptr, hbuf, nullptr, nullptr, nullptr);
    // MLP2 + residual: 64x64 BK=64 dbuf-prefetch, K=2048, grid 512
    // (round-7 falsified 128x64 @ 1 block/CU: 2 blocks/CU wins — keep 64x64)
    k_gemm<64, 64, 2, 2, 2, 2, 1><<<dim3(8, 64), 256, 0, stream>>>(
        hbuf, W2T, b2, 2048, 2048, 2048, 512, x1, (float*)d_out, nullptr, nullptr, nullptr, nullptr);
}